// Round 3
// baseline (1126.987 us; speedup 1.0000x reference)
//
#include <hip/hip_runtime.h>

// ---------------------------------------------------------------------------
// VM-LSTM: T=512, B=64, I=H=512, R=64.
// R3 theory: wave-uniform operands moved to scalar registers.
//  - k3: ds_read_b32 + v_readlane -> SGPR feeds v_dot2 (kills the 2x64KB/step
//    LDS broadcast traffic that bounded R2's step at ~3264 cyc).
//  - k1/k2: row-uniform data read with uniform indices from global -> s_load.
//  - x packed to f16 once (kp_pack), buffer aliased over gx (dead before k2).
// Workspace: ~132.7 MiB (same layout as R2).
// ---------------------------------------------------------------------------

typedef __fp16 h2f __attribute__((ext_vector_type(2)));
typedef unsigned int u32;
typedef unsigned short u16;

__device__ __forceinline__ float dot2f(u32 a, u32 b, float c) {
#if __has_builtin(__builtin_amdgcn_fdot2)
  return __builtin_amdgcn_fdot2(__builtin_bit_cast(h2f, a),
                                __builtin_bit_cast(h2f, b), c, false);
#else
  h2f x = __builtin_bit_cast(h2f, a);
  h2f y = __builtin_bit_cast(h2f, b);
  return c + (float)x[0] * (float)y[0] + (float)x[1] * (float)y[1];
#endif
}

__device__ __forceinline__ u32 pk2(float a, float b) {
#if __has_builtin(__builtin_amdgcn_cvt_pkrtz)
  return __builtin_bit_cast(u32, __builtin_amdgcn_cvt_pkrtz(a, b));
#else
  h2f h;
  h[0] = (__fp16)a;
  h[1] = (__fp16)b;
  return __builtin_bit_cast(u32, h);
#endif
}

__device__ __forceinline__ float h2f1(u16 u) {
  return (float)__builtin_bit_cast(__fp16, u);
}
__device__ __forceinline__ u16 f2h(float f) {
  return __builtin_bit_cast(u16, (__fp16)f);
}
__device__ __forceinline__ u32 rdlane(u32 v, int l) {
  return (u32)__builtin_amdgcn_readlane((int)v, l);
}

// select component of a uint4 by constant index (folds under full unroll)
#define Q4(q, j) ((j) == 0 ? (q).x : (j) == 1 ? (q).y : (j) == 2 ? (q).z : (q).w)

// ---------------------------------------------------------------------------
// K0: pack weights to f16 layouts + compute diagonal corrections Dx/Dh.
//  WxP/WhP: [j][r/2] pairs (j-major, 32 uints per row of 64)
//  UxP/UhP: [r][k/2] pairs (transposed, pairs along k)
//  Dx/Dh:   [g*512+h] = sum_r U[h,r]*W[g*512+h,r]
// ---------------------------------------------------------------------------
__global__ void k0_prep(const float* __restrict__ Wx, const float* __restrict__ Wh,
                        const float* __restrict__ Ux, const float* __restrict__ Uh,
                        u32* __restrict__ WxP, u32* __restrict__ WhP,
                        u32* __restrict__ UxP, u32* __restrict__ UhP,
                        float* __restrict__ Dx, float* __restrict__ Dh) {
  int idx = blockIdx.x * 256 + threadIdx.x;  // 65536 threads
  if (idx < 65536) {
    WxP[idx] = pk2(Wx[2 * idx], Wx[2 * idx + 1]);
    WhP[idx] = pk2(Wh[2 * idx], Wh[2 * idx + 1]);
  }
  if (idx < 16384) {
    int r = idx >> 8, k2 = idx & 255;
    UxP[idx] = pk2(Ux[(2 * k2) * 64 + r], Ux[(2 * k2 + 1) * 64 + r]);
    UhP[idx] = pk2(Uh[(2 * k2) * 64 + r], Uh[(2 * k2 + 1) * 64 + r]);
  }
  if (idx < 4096) {
    int which = idx >> 11;
    int j = idx & 2047;
    int h = j & 511;
    const float* U = which ? Uh : Ux;
    const float* W = which ? Wh : Wx;
    float s = 0.f;
    for (int r = 0; r < 64; r++) s += U[h * 64 + r] * W[j * 64 + r];
    (which ? Dh : Dx)[j] = s;
  }
}

// ---------------------------------------------------------------------------
// KP: pack x (f32) -> f16 pairs along k: xh16[row*256 + kk]. 4.19M threads.
// ---------------------------------------------------------------------------
__global__ void kp_pack(const float* __restrict__ x, u32* __restrict__ xh16) {
  int idx = blockIdx.x * 256 + threadIdx.x;  // 4,194,304 float4s
  float4 v = ((const float4*)x)[idx];
  xh16[2 * idx] = pk2(v.x, v.y);
  xh16[2 * idx + 1] = pk2(v.z, v.w);
}

// ---------------------------------------------------------------------------
// K1: xu[row][r] = sum_k x[row,k]*Ux[k,r]. Block 256 thr = 4 waves; each wave
// owns 16 rows, lane = r. x-row chunks are wave-uniform -> uniform loads from
// xh16 (s_load). U chunk per lane from L2, reused across 16 rows. Output
// packed to r-pairs via one shfl_xor.
// ---------------------------------------------------------------------------
__global__ __launch_bounds__(256) void k1_xu(const u32* __restrict__ xh16,
                                             const u32* __restrict__ UxP,
                                             u32* __restrict__ xuP) {
  const int t = threadIdx.x;
  const int w = t >> 6, r = t & 63;
  const int row0 = blockIdx.x * 64 + w * 16;
  float acc[16];
#pragma unroll
  for (int i = 0; i < 16; i++) acc[i] = 0.f;
  const uint4* Ub = (const uint4*)(UxP + r * 256);
  const uint4* xq = (const uint4*)xh16;  // [row*64 + kc*2]

  for (int kc = 0; kc < 32; kc++) {
    uint4 u0 = Ub[kc * 2], u1 = Ub[kc * 2 + 1];
#pragma unroll
    for (int row = 0; row < 16; row++) {
      uint4 s0 = xq[(size_t)(row0 + row) * 64 + kc * 2];      // uniform
      uint4 s1 = xq[(size_t)(row0 + row) * 64 + kc * 2 + 1];  // uniform
      float a = acc[row];
      a = dot2f(s0.x, u0.x, a);
      a = dot2f(s0.y, u0.y, a);
      a = dot2f(s0.z, u0.z, a);
      a = dot2f(s0.w, u0.w, a);
      a = dot2f(s1.x, u1.x, a);
      a = dot2f(s1.y, u1.y, a);
      a = dot2f(s1.z, u1.z, a);
      a = dot2f(s1.w, u1.w, a);
      acc[row] = a;
    }
  }
#pragma unroll
  for (int row = 0; row < 16; row++) {
    float o = __shfl_xor(acc[row], 1);
    if (!(r & 1)) xuP[(size_t)(row0 + row) * 32 + (r >> 1)] = pk2(acc[row], o);
  }
}

// ---------------------------------------------------------------------------
// K2: gx[row][g*512+h] = f16( sum_r xu[row,r]*Wx[g*512+h,r]
//                             + x[row,h]*(dia_x[h]-Dx[g,h]) + b_x[g*512+h] )
// Block 512 thr, 64 rows (W loaded once per block, amortized 4x vs R2).
// xu rows are wave-uniform -> uniform uint4 loads (s_load), no LDS at all.
// ---------------------------------------------------------------------------
__global__ __launch_bounds__(512, 2) void k2_gx(
    const float* __restrict__ x, const u32* __restrict__ xuP,
    const u32* __restrict__ WxP, const float* __restrict__ Dx,
    const float* __restrict__ bx, const float* __restrict__ diax,
    u16* __restrict__ gx) {
  const int t = threadIdx.x;
  const int rows0 = blockIdx.x * 64;

  uint4 Wp[4][8];
#pragma unroll
  for (int g = 0; g < 4; g++) {
    const uint4* p = (const uint4*)(WxP + (size_t)(g * 512 + t) * 32);
#pragma unroll
    for (int m = 0; m < 8; m++) Wp[g][m] = p[m];
  }
  const float dia = diax[t];
  float Dg[4], bg[4];
#pragma unroll
  for (int g = 0; g < 4; g++) {
    Dg[g] = Dx[g * 512 + t];
    bg[g] = bx[g * 512 + t];
  }
  const uint4* xuq = (const uint4*)xuP;  // [row*8 + m]

  for (int row = 0; row < 64; row++) {
    const int R = rows0 + row;
    uint4 s[8];
#pragma unroll
    for (int m = 0; m < 8; m++) s[m] = xuq[(size_t)R * 8 + m];  // uniform
    float xv = x[(size_t)R * 512 + t];
    u16* gout = gx + (size_t)R * 2048 + t;
    float a[4];
#pragma unroll
    for (int g = 0; g < 4; g++) {
      float ac = 0.f;
#pragma unroll
      for (int m = 0; m < 8; m++) {
        ac = dot2f(s[m].x, Wp[g][m].x, ac);
        ac = dot2f(s[m].y, Wp[g][m].y, ac);
        ac = dot2f(s[m].z, Wp[g][m].z, ac);
        ac = dot2f(s[m].w, Wp[g][m].w, ac);
      }
      a[g] = ac;
    }
#pragma unroll
    for (int g = 0; g < 4; g++) {
      gout[g * 512] = f2h(a[g] + xv * (dia - Dg[g]) + bg[g]);
    }
  }
}

// ---------------------------------------------------------------------------
// K3: recurrence. 64 WGs (one per batch) x 512 thr; thread t owns h-lane t.
// W_h rows (128 reg) + U_h column slice (32 reg) resident across 512 steps.
// Broadcast data (h chunk, hu) via 1 ds_read_b32/wave + v_readlane -> SGPR
// feeding v_dot2 (1 SGPR operand legal) -> LDS pipe ~idle. 3 barriers/step.
// ---------------------------------------------------------------------------
__global__ __launch_bounds__(512, 2) void k3_rnn(
    const u16* __restrict__ gx, const u32* __restrict__ WhP,
    const u32* __restrict__ UhP, const float* __restrict__ Dh,
    const float* __restrict__ bh, const float* __restrict__ diah,
    float* __restrict__ out) {
  __shared__ u32 h32[256];           // 512 h as f16 pairs
  __shared__ float partial[8 * 72];  // padded rows: bank = (8c + r) % 32, 2-way
  __shared__ u32 hu32[32];           // 64 hu as f16 pairs

  const int t = threadIdx.x;
  const int b = blockIdx.x;
  const int lane = t & 63;
  const int w = t >> 6;

  uint4 Wp[4][8];
#pragma unroll
  for (int g = 0; g < 4; g++) {
    const uint4* p = (const uint4*)(WhP + (size_t)(g * 512 + t) * 32);
#pragma unroll
    for (int m = 0; m < 8; m++) Wp[g][m] = p[m];
  }
  uint4 Up[8];
  {
    const uint4* p = (const uint4*)(UhP + lane * 256 + w * 32);
#pragma unroll
    for (int m = 0; m < 8; m++) Up[m] = p[m];
  }
  const float dia = diah[t];
  float Dg[4], bg[4];
#pragma unroll
  for (int g = 0; g < 4; g++) {
    Dg[g] = Dh[g * 512 + t];
    bg[g] = bh[g * 512 + t];
  }

  float h = 0.f, c = 0.f;
  if (t < 256) h32[t] = 0u;
  __syncthreads();

  const u16* gxb = gx + (size_t)b * 2048 + t;
  float* outb = out + (size_t)b * 512 + t;

  float gxl[4];
#pragma unroll
  for (int g = 0; g < 4; g++) gxl[g] = h2f1(gxb[g * 512]);

  for (int ts = 0; ts < 512; ts++) {
    // ---- stage A: partial hU; r = lane, h-chunk = w (wave-uniform)
    u32 vh = h32[(w << 5) + (t & 31)];  // lane m (m<32) holds pair w*32+m
    float acc = 0.f;
#pragma unroll
    for (int m = 0; m < 8; m++) {
      uint4 uq = Up[m];
      u32 s0 = rdlane(vh, 4 * m + 0);
      u32 s1 = rdlane(vh, 4 * m + 1);
      u32 s2 = rdlane(vh, 4 * m + 2);
      u32 s3 = rdlane(vh, 4 * m + 3);
      acc = dot2f(s0, uq.x, acc);
      acc = dot2f(s1, uq.y, acc);
      acc = dot2f(s2, uq.z, acc);
      acc = dot2f(s3, uq.w, acc);
    }
    partial[w * 72 + lane] = acc;
    __syncthreads();

    // prefetch next step's gx (consumed next iteration)
    const u16* gn = gxb + (size_t)(ts + (ts < 511)) * 131072;
    float gxn[4];
#pragma unroll
    for (int g = 0; g < 4; g++) gxn[g] = h2f1(gn[g * 512]);

    // ---- reduce across the 8 h-chunks, spread over all waves
    float p = partial[(t & 7) * 72 + (t >> 3)];
    p += __shfl_xor(p, 1);
    p += __shfl_xor(p, 2);
    p += __shfl_xor(p, 4);
    float q = __shfl_xor(p, 8);
    if ((t & 15) == 0) hu32[t >> 4] = pk2(p, q);
    __syncthreads();

    // ---- stage B: 4 gate dots, hu via readlane -> SGPR
    u32 vhu = hu32[t & 31];
    float a0 = 0.f, a1 = 0.f, a2 = 0.f, a3 = 0.f;
#pragma unroll
    for (int m = 0; m < 8; m++) {
      uint4 w0 = Wp[0][m], w1 = Wp[1][m], w2 = Wp[2][m], w3 = Wp[3][m];
      u32 s0 = rdlane(vhu, 4 * m + 0);
      u32 s1 = rdlane(vhu, 4 * m + 1);
      u32 s2 = rdlane(vhu, 4 * m + 2);
      u32 s3 = rdlane(vhu, 4 * m + 3);
      a0 = dot2f(s0, w0.x, a0); a0 = dot2f(s1, w0.y, a0);
      a0 = dot2f(s2, w0.z, a0); a0 = dot2f(s3, w0.w, a0);
      a1 = dot2f(s0, w1.x, a1); a1 = dot2f(s1, w1.y, a1);
      a1 = dot2f(s2, w1.z, a1); a1 = dot2f(s3, w1.w, a1);
      a2 = dot2f(s0, w2.x, a2); a2 = dot2f(s1, w2.y, a2);
      a2 = dot2f(s2, w2.z, a2); a2 = dot2f(s3, w2.w, a2);
      a3 = dot2f(s0, w3.x, a3); a3 = dot2f(s1, w3.y, a3);
      a3 = dot2f(s2, w3.z, a3); a3 = dot2f(s3, w3.w, a3);
    }
    float pre0 = a0 + gxl[0] + h * (dia - Dg[0]) + bg[0];
    float pre1 = a1 + gxl[1] + h * (dia - Dg[1]) + bg[1];
    float pre2 = a2 + gxl[2] + h * (dia - Dg[2]) + bg[2];
    float pre3 = a3 + gxl[3] + h * (dia - Dg[3]) + bg[3];

    float ig = 1.f / (1.f + __expf(-pre0));
    float fg = 1.f / (1.f + __expf(-pre1));
    float og = 1.f / (1.f + __expf(-pre2));
    float e2 = __expf(2.f * pre3);
    float ng = 1.f - 2.f / (e2 + 1.f);
    c = fg * c + ig * ng;
    float e2c = __expf(2.f * c);
    h = og * (1.f - 2.f / (e2c + 1.f));

    outb[(size_t)ts * 32768] = h;
    ((u16*)h32)[t] = f2h(h);
#pragma unroll
    for (int g = 0; g < 4; g++) gxl[g] = gxn[g];
    __syncthreads();
  }
  out[(size_t)512 * 32768 + (size_t)b * 512 + t] = h;
  out[(size_t)512 * 32768 + 32768 + (size_t)b * 512 + t] = c;
}

// ---------------------------------------------------------------------------
extern "C" void kernel_launch(void* const* d_in, const int* in_sizes, int n_in,
                              void* d_out, int out_size, void* d_ws,
                              size_t ws_size, hipStream_t stream) {
  const float* x = (const float*)d_in[0];
  // d_in[1]=h0, d_in[2]=c0: zeros by construction (recurrence inits 0)
  const float* Ux = (const float*)d_in[3];
  const float* Uh = (const float*)d_in[4];
  const float* Wx = (const float*)d_in[5];
  const float* Wh = (const float*)d_in[6];
  const float* bx = (const float*)d_in[7];
  const float* bh = (const float*)d_in[8];
  const float* diax = (const float*)d_in[9];
  const float* diah = (const float*)d_in[10];
  float* out = (float*)d_out;

  // workspace layout (bytes); total ~139,083,776 B (~132.7 MiB)
  char* ws = (char*)d_ws;
  u16* gx = (u16*)ws;                    // 512*64*2048 f16 = 134217728
  u32* xh16 = (u32*)ws;                  // 33.5 MB, ALIASES gx (dead pre-k2)
  u32* xuP = (u32*)(ws + 134217728);     // 32768*32 u32   =   4194304
  u32* WxP = (u32*)(ws + 138412032);     // 65536 u32      =    262144
  u32* WhP = (u32*)(ws + 138674176);     // 65536 u32      =    262144
  u32* UxP = (u32*)(ws + 138936320);     // 16384 u32      =     65536
  u32* UhP = (u32*)(ws + 139001856);     // 16384 u32      =     65536
  float* Dx = (float*)(ws + 139067392);  // 2048 f32       =      8192
  float* Dh = (float*)(ws + 139075584);  // 2048 f32       =      8192

  k0_prep<<<256, 256, 0, stream>>>(Wx, Wh, Ux, Uh, WxP, WhP, UxP, UhP, Dx, Dh);
  kp_pack<<<16384, 256, 0, stream>>>(x, xh16);
  k1_xu<<<512, 256, 0, stream>>>(xh16, UxP, xuP);
  k2_gx<<<512, 512, 0, stream>>>(x, xuP, WxP, Dx, bx, diax, gx);
  k3_rnn<<<64, 512, 0, stream>>>(gx, WhP, UhP, Dh, bh, diah, out);
}

// Round 4
// 1084.482 us; speedup vs baseline: 1.0392x; 1.0392x over previous
//
#include <hip/hip_runtime.h>

// ---------------------------------------------------------------------------
// VM-LSTM: T=512, B=64, I=H=512, R=64.
// R4: k3 at 1024 thr/WG (4 waves/SIMD), 16-chunk stage A, all-wave shfl
// reduce, r-split stage B with float4 LDS exchange, interleaved gx (ushort4)
// with 1-step prefetch. Broadcast b128 LDS reads everywhere (R3 readlane
// scheme removed — VALU->SGPR hazards made it a 20% regression).
// ---------------------------------------------------------------------------

typedef __fp16 h2f __attribute__((ext_vector_type(2)));
typedef unsigned int u32;
typedef unsigned short u16;

__device__ __forceinline__ float dot2f(u32 a, u32 b, float c) {
#if __has_builtin(__builtin_amdgcn_fdot2)
  return __builtin_amdgcn_fdot2(__builtin_bit_cast(h2f, a),
                                __builtin_bit_cast(h2f, b), c, false);
#else
  h2f x = __builtin_bit_cast(h2f, a);
  h2f y = __builtin_bit_cast(h2f, b);
  return c + (float)x[0] * (float)y[0] + (float)x[1] * (float)y[1];
#endif
}

__device__ __forceinline__ u32 pk2(float a, float b) {
#if __has_builtin(__builtin_amdgcn_cvt_pkrtz)
  return __builtin_bit_cast(u32, __builtin_amdgcn_cvt_pkrtz(a, b));
#else
  h2f h;
  h[0] = (__fp16)a;
  h[1] = (__fp16)b;
  return __builtin_bit_cast(u32, h);
#endif
}

__device__ __forceinline__ float h2f1(u16 u) {
  return (float)__builtin_bit_cast(__fp16, u);
}
__device__ __forceinline__ u16 f2h(float f) {
  return __builtin_bit_cast(u16, (__fp16)f);
}

// ---------------------------------------------------------------------------
// K0: pack weights to f16 layouts + compute diagonal corrections Dx/Dh.
//  WxP/WhP: [j][r/2] pairs (j-major, 32 uints per row of 64)
//  UxP/UhP: [r][k/2] pairs (transposed, pairs along k)
//  Dx/Dh:   [g*512+h] = sum_r U[h,r]*W[g*512+h,r]
// ---------------------------------------------------------------------------
__global__ void k0_prep(const float* __restrict__ Wx, const float* __restrict__ Wh,
                        const float* __restrict__ Ux, const float* __restrict__ Uh,
                        u32* __restrict__ WxP, u32* __restrict__ WhP,
                        u32* __restrict__ UxP, u32* __restrict__ UhP,
                        float* __restrict__ Dx, float* __restrict__ Dh) {
  int idx = blockIdx.x * 256 + threadIdx.x;  // 65536 threads
  if (idx < 65536) {
    WxP[idx] = pk2(Wx[2 * idx], Wx[2 * idx + 1]);
    WhP[idx] = pk2(Wh[2 * idx], Wh[2 * idx + 1]);
  }
  if (idx < 16384) {
    int r = idx >> 8, k2 = idx & 255;
    UxP[idx] = pk2(Ux[(2 * k2) * 64 + r], Ux[(2 * k2 + 1) * 64 + r]);
    UhP[idx] = pk2(Uh[(2 * k2) * 64 + r], Uh[(2 * k2 + 1) * 64 + r]);
  }
  if (idx < 4096) {
    int which = idx >> 11;
    int j = idx & 2047;
    int h = j & 511;
    const float* U = which ? Uh : Ux;
    const float* W = which ? Wh : Wx;
    float s = 0.f;
    for (int r = 0; r < 64; r++) s += U[h * 64 + r] * W[j * 64 + r];
    (which ? Dh : Dx)[j] = s;
  }
}

// ---------------------------------------------------------------------------
// K1 (R2-proven): xu[row][r] = sum_k x[row,k]*Ux[k,r], packed f16 [row][r/2].
// 256 thr, 32 rows/block; x staged to LDS as f16 pairs, broadcast b128 reads.
// ---------------------------------------------------------------------------
__global__ __launch_bounds__(256) void k1_xu(const float* __restrict__ x,
                                             const u32* __restrict__ UxP,
                                             u32* __restrict__ xuP) {
  __shared__ alignas(16) u32 xh[8192];  // 32 rows x 256 pair-uints (32 KiB)
  const int tid = threadIdx.x;
  const int row0 = blockIdx.x * 32;
  const float* xs = x + (size_t)row0 * 512;

#pragma unroll
  for (int i = 0; i < 16; i++) {
    int f = tid + i * 256;  // float4 index, 4096 total
    float4 v = ((const float4*)xs)[f];
    xh[f * 2] = pk2(v.x, v.y);
    xh[f * 2 + 1] = pk2(v.z, v.w);
  }
  __syncthreads();

  const int w = tid >> 6, r = tid & 63;
  const int wr0 = w * 8;
  float acc[8] = {0.f, 0.f, 0.f, 0.f, 0.f, 0.f, 0.f, 0.f};
  const u32* Ubase = UxP + r * 256;

  for (int kc = 0; kc < 32; kc++) {
    uint4 u0 = *(const uint4*)(Ubase + kc * 8);
    uint4 u1 = *(const uint4*)(Ubase + kc * 8 + 4);
#pragma unroll
    for (int row = 0; row < 8; row++) {
      const uint4* xp = (const uint4*)&xh[(wr0 + row) * 256 + kc * 8];
      uint4 a0 = xp[0], a1 = xp[1];
      float a = acc[row];
      a = dot2f(a0.x, u0.x, a);
      a = dot2f(a0.y, u0.y, a);
      a = dot2f(a0.z, u0.z, a);
      a = dot2f(a0.w, u0.w, a);
      a = dot2f(a1.x, u1.x, a);
      a = dot2f(a1.y, u1.y, a);
      a = dot2f(a1.z, u1.z, a);
      a = dot2f(a1.w, u1.w, a);
      acc[row] = a;
    }
  }
#pragma unroll
  for (int row = 0; row < 8; row++) {
    float other = __shfl_xor(acc[row], 1, 64);
    if ((r & 1) == 0) {
      xuP[(size_t)(row0 + wr0 + row) * 32 + (r >> 1)] = pk2(acc[row], other);
    }
  }
}

// ---------------------------------------------------------------------------
// K2: gx[row][j][g] (ushort4-interleaved) =
//   f16( sum_r xu[row,r]*Wx[g*512+j,r] + x[row,j]*(dia_x-Dx) + b_x )
// 512 thr, 64 rows/block; xu rows staged to LDS once, broadcast b128 reads;
// W rows resident in 128 VGPR; one coalesced ushort4 store per row.
// ---------------------------------------------------------------------------
__global__ __launch_bounds__(512, 2) void k2_gx(
    const float* __restrict__ x, const u32* __restrict__ xuP,
    const u32* __restrict__ WxP, const float* __restrict__ Dx,
    const float* __restrict__ bx, const float* __restrict__ diax,
    u16* __restrict__ gx) {
  __shared__ alignas(16) u32 xus[2048];  // 64 rows x 32 pair-uints (8 KiB)
  const int t = threadIdx.x;
  const int rows0 = blockIdx.x * 64;

  uint4 Wp[4][8];
#pragma unroll
  for (int g = 0; g < 4; g++) {
    const uint4* p = (const uint4*)(WxP + (size_t)(g * 512 + t) * 32);
#pragma unroll
    for (int m = 0; m < 8; m++) Wp[g][m] = p[m];
  }
  const float dia = diax[t];
  float Dg[4], bg[4];
#pragma unroll
  for (int g = 0; g < 4; g++) {
    Dg[g] = Dx[g * 512 + t];
    bg[g] = bx[g * 512 + t];
  }
#pragma unroll
  for (int i = 0; i < 4; i++) xus[t + i * 512] = xuP[(size_t)rows0 * 32 + t + i * 512];
  __syncthreads();

  ushort4* gx4 = (ushort4*)gx;
  for (int row = 0; row < 64; row++) {
    const int R = rows0 + row;
    const uint4* s = (const uint4*)(xus + row * 32);
    float xv = x[(size_t)R * 512 + t];
    float a0 = 0.f, a1 = 0.f, a2 = 0.f, a3 = 0.f;
#pragma unroll
    for (int m = 0; m < 8; m++) {
      uint4 sm = s[m];
      uint4 w0 = Wp[0][m], w1 = Wp[1][m], w2 = Wp[2][m], w3 = Wp[3][m];
      a0 = dot2f(sm.x, w0.x, a0); a0 = dot2f(sm.y, w0.y, a0);
      a0 = dot2f(sm.z, w0.z, a0); a0 = dot2f(sm.w, w0.w, a0);
      a1 = dot2f(sm.x, w1.x, a1); a1 = dot2f(sm.y, w1.y, a1);
      a1 = dot2f(sm.z, w1.z, a1); a1 = dot2f(sm.w, w1.w, a1);
      a2 = dot2f(sm.x, w2.x, a2); a2 = dot2f(sm.y, w2.y, a2);
      a2 = dot2f(sm.z, w2.z, a2); a2 = dot2f(sm.w, w2.w, a2);
      a3 = dot2f(sm.x, w3.x, a3); a3 = dot2f(sm.y, w3.y, a3);
      a3 = dot2f(sm.z, w3.z, a3); a3 = dot2f(sm.w, w3.w, a3);
    }
    ushort4 o;
    o.x = f2h(a0 + xv * (dia - Dg[0]) + bg[0]);
    o.y = f2h(a1 + xv * (dia - Dg[1]) + bg[1]);
    o.z = f2h(a2 + xv * (dia - Dg[2]) + bg[2]);
    o.w = f2h(a3 + xv * (dia - Dg[3]) + bg[3]);
    gx4[(size_t)R * 512 + t] = o;
  }
}

// ---------------------------------------------------------------------------
// K3: recurrence. 64 WGs (one per batch) x 1024 thr (16 waves, 4/SIMD).
//  j = t&511 (h-lane), half = t>>9 (r-half for stage B), w = t>>6 (chunk).
//  Stage A: chunk w = 32 h, r = lane: 16 dot2 -> partial[w][r].
//  Reduce: all waves, shfl butterfly over 16-lane groups -> hu (f16 pairs).
//  Stage B: 4 gates x 16 r-pairs (own half) = 64 dot2; half1 sends partial
//  pre via float4 LDS; half0 finishes gates, updates c/h, writes out + h16.
//  gx interleaved ushort4, prefetched one step ahead. 4 barriers/step.
// ---------------------------------------------------------------------------
__global__ __launch_bounds__(1024) void k3_rnn(
    const u16* __restrict__ gx, const u32* __restrict__ WhP,
    const u32* __restrict__ UhP, const float* __restrict__ Dh,
    const float* __restrict__ bh, const float* __restrict__ diah,
    float* __restrict__ out) {
  __shared__ alignas(16) u32 h32[256];    // 512 h as f16 pairs
  __shared__ float partial[16 * 68];      // stride 68: 2-way banks only
  __shared__ alignas(16) u32 hu32[32];    // 64 hu as f16 pairs
  __shared__ alignas(16) float4 preB[512];

  const int t = threadIdx.x;
  const int b = blockIdx.x;
  const int lane = t & 63;
  const int w = t >> 6;    // 0..15: stage-A chunk
  const int j = t & 511;   // h-lane
  const int half = t >> 9; // 0/1: stage-B r-half

  uint4 Wp[4][4];
#pragma unroll
  for (int g = 0; g < 4; g++) {
    const uint4* p = (const uint4*)(WhP + (size_t)(g * 512 + j) * 32 + half * 16);
#pragma unroll
    for (int m = 0; m < 4; m++) Wp[g][m] = p[m];
  }
  uint4 Up[4];
  {
    const uint4* p = (const uint4*)(UhP + lane * 256 + w * 16);
#pragma unroll
    for (int m = 0; m < 4; m++) Up[m] = p[m];
  }
  float dia = 0.f, Dg[4] = {0.f, 0.f, 0.f, 0.f}, bg[4] = {0.f, 0.f, 0.f, 0.f};
  if (half == 0) {
    dia = diah[j];
#pragma unroll
    for (int g = 0; g < 4; g++) {
      Dg[g] = Dh[g * 512 + j];
      bg[g] = bh[g * 512 + j];
    }
  }

  float h = 0.f, c = 0.f;
  if (t < 256) h32[t] = 0u;
  __syncthreads();

  const ushort4* gx4 = (const ushort4*)gx;  // [(ts*64+b)*512 + j]
  const size_t gbase = (size_t)b * 512 + j;
  float* outb = out + (size_t)b * 512 + j;

  ushort4 gcur = {0, 0, 0, 0};
  if (half == 0) gcur = gx4[gbase];

  for (int ts = 0; ts < 512; ts++) {
    // prefetch next step's gx (half0 only); waits only at gate finalize
    ushort4 gnext = gcur;
    if (half == 0) {
      int tn = ts + (ts < 511);
      gnext = gx4[(size_t)tn * 32768 + gbase];
    }

    // ---- stage A: partial hU over chunk w (32 h = 16 pairs), r = lane
    const uint4* hp = ((const uint4*)h32) + w * 4;
    float acc = 0.f;
#pragma unroll
    for (int m = 0; m < 4; m++) {
      uint4 hv = hp[m];
      uint4 uq = Up[m];
      acc = dot2f(hv.x, uq.x, acc);
      acc = dot2f(hv.y, uq.y, acc);
      acc = dot2f(hv.z, uq.z, acc);
      acc = dot2f(hv.w, uq.w, acc);
    }
    partial[w * 68 + lane] = acc;
    __syncthreads();

    // ---- reduce: 16 chunks -> hu_r, spread over all 16 waves
    float pv = partial[(t & 15) * 68 + (t >> 4)];
    pv += __shfl_xor(pv, 1);
    pv += __shfl_xor(pv, 2);
    pv += __shfl_xor(pv, 4);
    pv += __shfl_xor(pv, 8);
    float qv = __shfl_xor(pv, 16);
    if ((lane & 31) == 0) hu32[2 * w + (lane >> 5)] = pk2(pv, qv);
    __syncthreads();

    // ---- stage B: 4 gates x own r-half (16 pairs)
    const uint4* hup = ((const uint4*)hu32) + half * 4;
    float a0 = 0.f, a1 = 0.f, a2 = 0.f, a3 = 0.f;
#pragma unroll
    for (int m = 0; m < 4; m++) {
      uint4 hm = hup[m];
      uint4 w0 = Wp[0][m], w1 = Wp[1][m], w2 = Wp[2][m], w3 = Wp[3][m];
      a0 = dot2f(hm.x, w0.x, a0); a0 = dot2f(hm.y, w0.y, a0);
      a0 = dot2f(hm.z, w0.z, a0); a0 = dot2f(hm.w, w0.w, a0);
      a1 = dot2f(hm.x, w1.x, a1); a1 = dot2f(hm.y, w1.y, a1);
      a1 = dot2f(hm.z, w1.z, a1); a1 = dot2f(hm.w, w1.w, a1);
      a2 = dot2f(hm.x, w2.x, a2); a2 = dot2f(hm.y, w2.y, a2);
      a2 = dot2f(hm.z, w2.z, a2); a2 = dot2f(hm.w, w2.w, a2);
      a3 = dot2f(hm.x, w3.x, a3); a3 = dot2f(hm.y, w3.y, a3);
      a3 = dot2f(hm.z, w3.z, a3); a3 = dot2f(hm.w, w3.w, a3);
    }
    if (half == 1) {
      float4 v; v.x = a0; v.y = a1; v.z = a2; v.w = a3;
      preB[j] = v;
    }
    __syncthreads();

    if (half == 0) {
      float4 pb = preB[j];
      float pre0 = a0 + pb.x + h2f1(gcur.x) + h * (dia - Dg[0]) + bg[0];
      float pre1 = a1 + pb.y + h2f1(gcur.y) + h * (dia - Dg[1]) + bg[1];
      float pre2 = a2 + pb.z + h2f1(gcur.z) + h * (dia - Dg[2]) + bg[2];
      float pre3 = a3 + pb.w + h2f1(gcur.w) + h * (dia - Dg[3]) + bg[3];
      float ig = 1.f / (1.f + __expf(-pre0));
      float fg = 1.f / (1.f + __expf(-pre1));
      float og = 1.f / (1.f + __expf(-pre2));
      float e2 = __expf(2.f * pre3);
      float ng = 1.f - 2.f / (e2 + 1.f);
      c = fg * c + ig * ng;
      float e2c = __expf(2.f * c);
      h = og * (1.f - 2.f / (e2c + 1.f));
      outb[(size_t)ts * 32768] = h;
      ((u16*)h32)[j] = f2h(h);
    }
    gcur = gnext;
    __syncthreads();
  }
  if (half == 0) {
    out[(size_t)512 * 32768 + (size_t)b * 512 + j] = h;
    out[(size_t)512 * 32768 + 32768 + (size_t)b * 512 + j] = c;
  }
}

// ---------------------------------------------------------------------------
extern "C" void kernel_launch(void* const* d_in, const int* in_sizes, int n_in,
                              void* d_out, int out_size, void* d_ws,
                              size_t ws_size, hipStream_t stream) {
  const float* x = (const float*)d_in[0];
  // d_in[1]=h0, d_in[2]=c0: zeros by construction (recurrence inits 0)
  const float* Ux = (const float*)d_in[3];
  const float* Uh = (const float*)d_in[4];
  const float* Wx = (const float*)d_in[5];
  const float* Wh = (const float*)d_in[6];
  const float* bx = (const float*)d_in[7];
  const float* bh = (const float*)d_in[8];
  const float* diax = (const float*)d_in[9];
  const float* diah = (const float*)d_in[10];
  float* out = (float*)d_out;

  // workspace layout (bytes); total ~139,083,776 B (~132.7 MiB)
  char* ws = (char*)d_ws;
  u16* gx = (u16*)ws;                    // 32768 rows x 512 j x 4 g = 134217728
  u32* xuP = (u32*)(ws + 134217728);     // 32768*32 u32   =   4194304
  u32* WxP = (u32*)(ws + 138412032);     // 65536 u32      =    262144
  u32* WhP = (u32*)(ws + 138674176);     // 65536 u32      =    262144
  u32* UxP = (u32*)(ws + 138936320);     // 16384 u32      =     65536
  u32* UhP = (u32*)(ws + 139001856);     // 16384 u32      =     65536
  float* Dx = (float*)(ws + 139067392);  // 2048 f32       =      8192
  float* Dh = (float*)(ws + 139075584);  // 2048 f32       =      8192

  k0_prep<<<256, 256, 0, stream>>>(Wx, Wh, Ux, Uh, WxP, WhP, UxP, UhP, Dx, Dh);
  k1_xu<<<1024, 256, 0, stream>>>(x, UxP, xuP);
  k2_gx<<<512, 512, 0, stream>>>(x, xuP, WxP, Dx, bx, diax, gx);
  k3_rnn<<<64, 1024, 0, stream>>>(gx, WhP, UhP, Dh, bh, diah, out);
}

// Round 5
// 933.647 us; speedup vs baseline: 1.2071x; 1.1616x over previous
//
#include <hip/hip_runtime.h>

// ---------------------------------------------------------------------------
// VM-LSTM: T=512, B=64, I=H=512, R=64.
// R5: k3 = 2 barriers/step. Stage A (wave-uniform b128 h reads) -> barrier ->
// per-wave redundant hu reduce (no barrier: same-wave LDS write->read) ->
// stage B (128 dot2, ILP4) + update -> barrier. gx ushort4-interleaved with
// 1-step prefetch. k0 D-part now coalesced wave-butterfly.
// History: R3 readlane->SGPR = -20% (hazards); R4 16-wave + preB float4
// exchange = -23% (8-way conflicts + 4th barrier). Broadcast b128 is cheap.
// ---------------------------------------------------------------------------

typedef __fp16 h2f __attribute__((ext_vector_type(2)));
typedef unsigned int u32;
typedef unsigned short u16;

__device__ __forceinline__ float dot2f(u32 a, u32 b, float c) {
#if __has_builtin(__builtin_amdgcn_fdot2)
  return __builtin_amdgcn_fdot2(__builtin_bit_cast(h2f, a),
                                __builtin_bit_cast(h2f, b), c, false);
#else
  h2f x = __builtin_bit_cast(h2f, a);
  h2f y = __builtin_bit_cast(h2f, b);
  return c + (float)x[0] * (float)y[0] + (float)x[1] * (float)y[1];
#endif
}

__device__ __forceinline__ u32 pk2(float a, float b) {
#if __has_builtin(__builtin_amdgcn_cvt_pkrtz)
  return __builtin_bit_cast(u32, __builtin_amdgcn_cvt_pkrtz(a, b));
#else
  h2f h;
  h[0] = (__fp16)a;
  h[1] = (__fp16)b;
  return __builtin_bit_cast(u32, h);
#endif
}

__device__ __forceinline__ float h2f1(u16 u) {
  return (float)__builtin_bit_cast(__fp16, u);
}
__device__ __forceinline__ u16 f2h(float f) {
  return __builtin_bit_cast(u16, (__fp16)f);
}

// ---------------------------------------------------------------------------
// K0a: pack weights to f16 layouts.
//  WxP/WhP: [j][r/2] pairs (j-major, 32 uints per row of 64)
//  UxP/UhP: [r][k/2] pairs (transposed, pairs along k)
// ---------------------------------------------------------------------------
__global__ void k0a_pack(const float* __restrict__ Wx, const float* __restrict__ Wh,
                         const float* __restrict__ Ux, const float* __restrict__ Uh,
                         u32* __restrict__ WxP, u32* __restrict__ WhP,
                         u32* __restrict__ UxP, u32* __restrict__ UhP) {
  int idx = blockIdx.x * 256 + threadIdx.x;  // 65536 threads
  WxP[idx] = pk2(Wx[2 * idx], Wx[2 * idx + 1]);
  WhP[idx] = pk2(Wh[2 * idx], Wh[2 * idx + 1]);
  if (idx < 16384) {
    int r = idx >> 8, k2 = idx & 255;
    UxP[idx] = pk2(Ux[(2 * k2) * 64 + r], Ux[(2 * k2 + 1) * 64 + r]);
    UhP[idx] = pk2(Uh[(2 * k2) * 64 + r], Uh[(2 * k2 + 1) * 64 + r]);
  }
}

// ---------------------------------------------------------------------------
// K0b: D[g*512+h] = sum_r U[h,r]*W[g*512+h,r] for (Ux,Wx)->Dx, (Uh,Wh)->Dh.
// 64 blocks x 256 thr = 4 waves; each wave: 16 outputs, lane=r, coalesced
// 64-lane loads + butterfly reduce.
// ---------------------------------------------------------------------------
__global__ __launch_bounds__(256) void k0b_diag(
    const float* __restrict__ Ux, const float* __restrict__ Uh,
    const float* __restrict__ Wx, const float* __restrict__ Wh,
    float* __restrict__ Dx, float* __restrict__ Dh) {
  const int t = threadIdx.x;
  const int lane = t & 63;
  const int gw = blockIdx.x * 4 + (t >> 6);  // 0..255 waves
  for (int i = 0; i < 16; i++) {
    int o = gw * 16 + i;  // 0..4095
    int which = o >> 11;
    int j = o & 2047;
    int h = j & 511;
    const float* U = which ? Uh : Ux;
    const float* W = which ? Wh : Wx;
    float v = U[h * 64 + lane] * W[j * 64 + lane];
    v += __shfl_xor(v, 1);
    v += __shfl_xor(v, 2);
    v += __shfl_xor(v, 4);
    v += __shfl_xor(v, 8);
    v += __shfl_xor(v, 16);
    v += __shfl_xor(v, 32);
    if (lane == 0) (which ? Dh : Dx)[j] = v;
  }
}

// ---------------------------------------------------------------------------
// K1: xu[row][r] = sum_k x[row,k]*Ux[k,r], packed f16 [row][r/2].
// 256 thr, 32 rows/block; x staged to LDS as f16 pairs, broadcast b128 reads.
// ---------------------------------------------------------------------------
__global__ __launch_bounds__(256) void k1_xu(const float* __restrict__ x,
                                             const u32* __restrict__ UxP,
                                             u32* __restrict__ xuP) {
  __shared__ alignas(16) u32 xh[8192];  // 32 rows x 256 pair-uints (32 KiB)
  const int tid = threadIdx.x;
  const int row0 = blockIdx.x * 32;
  const float* xs = x + (size_t)row0 * 512;

#pragma unroll
  for (int i = 0; i < 16; i++) {
    int f = tid + i * 256;  // float4 index, 4096 total
    float4 v = ((const float4*)xs)[f];
    xh[f * 2] = pk2(v.x, v.y);
    xh[f * 2 + 1] = pk2(v.z, v.w);
  }
  __syncthreads();

  const int w = tid >> 6, r = tid & 63;
  const int wr0 = w * 8;
  float acc[8] = {0.f, 0.f, 0.f, 0.f, 0.f, 0.f, 0.f, 0.f};
  const u32* Ubase = UxP + r * 256;

  for (int kc = 0; kc < 32; kc++) {
    uint4 u0 = *(const uint4*)(Ubase + kc * 8);
    uint4 u1 = *(const uint4*)(Ubase + kc * 8 + 4);
#pragma unroll
    for (int row = 0; row < 8; row++) {
      const uint4* xp = (const uint4*)&xh[(wr0 + row) * 256 + kc * 8];
      uint4 a0 = xp[0], a1 = xp[1];
      float a = acc[row];
      a = dot2f(a0.x, u0.x, a);
      a = dot2f(a0.y, u0.y, a);
      a = dot2f(a0.z, u0.z, a);
      a = dot2f(a0.w, u0.w, a);
      a = dot2f(a1.x, u1.x, a);
      a = dot2f(a1.y, u1.y, a);
      a = dot2f(a1.z, u1.z, a);
      a = dot2f(a1.w, u1.w, a);
      acc[row] = a;
    }
  }
#pragma unroll
  for (int row = 0; row < 8; row++) {
    float other = __shfl_xor(acc[row], 1, 64);
    if ((r & 1) == 0) {
      xuP[(size_t)(row0 + wr0 + row) * 32 + (r >> 1)] = pk2(acc[row], other);
    }
  }
}

// ---------------------------------------------------------------------------
// K2: gx[row][j][g] (ushort4-interleaved) =
//   f16( sum_r xu[row,r]*Wx[g*512+j,r] + x[row,j]*(dia_x-Dx) + b_x )
// 512 thr, 64 rows/block; xu rows staged to LDS once, broadcast b128 reads;
// W rows resident in 128 VGPR; one coalesced ushort4 store per row.
// ---------------------------------------------------------------------------
__global__ __launch_bounds__(512, 2) void k2_gx(
    const float* __restrict__ x, const u32* __restrict__ xuP,
    const u32* __restrict__ WxP, const float* __restrict__ Dx,
    const float* __restrict__ bx, const float* __restrict__ diax,
    u16* __restrict__ gx) {
  __shared__ alignas(16) u32 xus[2048];  // 64 rows x 32 pair-uints (8 KiB)
  const int t = threadIdx.x;
  const int rows0 = blockIdx.x * 64;

  uint4 Wp[4][8];
#pragma unroll
  for (int g = 0; g < 4; g++) {
    const uint4* p = (const uint4*)(WxP + (size_t)(g * 512 + t) * 32);
#pragma unroll
    for (int m = 0; m < 8; m++) Wp[g][m] = p[m];
  }
  const float dia = diax[t];
  float Dg[4], bg[4];
#pragma unroll
  for (int g = 0; g < 4; g++) {
    Dg[g] = Dx[g * 512 + t];
    bg[g] = bx[g * 512 + t];
  }
#pragma unroll
  for (int i = 0; i < 4; i++) xus[t + i * 512] = xuP[(size_t)rows0 * 32 + t + i * 512];
  __syncthreads();

  ushort4* gx4 = (ushort4*)gx;
  for (int row = 0; row < 64; row++) {
    const int R = rows0 + row;
    const uint4* s = (const uint4*)(xus + row * 32);
    float xv = x[(size_t)R * 512 + t];
    float a0 = 0.f, a1 = 0.f, a2 = 0.f, a3 = 0.f;
#pragma unroll
    for (int m = 0; m < 8; m++) {
      uint4 sm = s[m];
      uint4 w0 = Wp[0][m], w1 = Wp[1][m], w2 = Wp[2][m], w3 = Wp[3][m];
      a0 = dot2f(sm.x, w0.x, a0); a0 = dot2f(sm.y, w0.y, a0);
      a0 = dot2f(sm.z, w0.z, a0); a0 = dot2f(sm.w, w0.w, a0);
      a1 = dot2f(sm.x, w1.x, a1); a1 = dot2f(sm.y, w1.y, a1);
      a1 = dot2f(sm.z, w1.z, a1); a1 = dot2f(sm.w, w1.w, a1);
      a2 = dot2f(sm.x, w2.x, a2); a2 = dot2f(sm.y, w2.y, a2);
      a2 = dot2f(sm.z, w2.z, a2); a2 = dot2f(sm.w, w2.w, a2);
      a3 = dot2f(sm.x, w3.x, a3); a3 = dot2f(sm.y, w3.y, a3);
      a3 = dot2f(sm.z, w3.z, a3); a3 = dot2f(sm.w, w3.w, a3);
    }
    ushort4 o;
    o.x = f2h(a0 + xv * (dia - Dg[0]) + bg[0]);
    o.y = f2h(a1 + xv * (dia - Dg[1]) + bg[1]);
    o.z = f2h(a2 + xv * (dia - Dg[2]) + bg[2]);
    o.w = f2h(a3 + xv * (dia - Dg[3]) + bg[3]);
    gx4[(size_t)R * 512 + t] = o;
  }
}

// ---------------------------------------------------------------------------
// K3: recurrence. 64 WGs (one per batch) x 512 thr (8 waves), thread t owns
// h-lane j=t. 2 barriers/step:
//   [bar] stage A: wave-uniform b128 reads of h chunk w=t>>6 (64 h), 32 dot2
//         (2 chains) -> partial[w*68+lane]
//   [bar] per-wave redundant reduce: 8x ds_read_b32 col lane -> hu[lane],
//         shfl pack -> per-wave huW region, lgkmcnt only (same wave),
//         8x b128 broadcast back; stage B 128 dot2 ILP4; update; h16 write.
// gx ushort4-interleaved, prefetched at segment top.
// ---------------------------------------------------------------------------
__global__ __launch_bounds__(512, 2) void k3_rnn(
    const u16* __restrict__ gx, const u32* __restrict__ WhP,
    const u32* __restrict__ UhP, const float* __restrict__ Dh,
    const float* __restrict__ bh, const float* __restrict__ diah,
    float* __restrict__ out) {
  __shared__ alignas(16) u32 h32[256];   // 512 h as f16 pairs
  __shared__ float partial[8 * 68];      // [chunk][r], stride 68
  __shared__ alignas(16) u32 huW[8 * 32];  // per-wave hu copies (f16 pairs)

  const int t = threadIdx.x;
  const int b = blockIdx.x;
  const int lane = t & 63;
  const int w = t >> 6;  // wave id = stage-A h-chunk

  uint4 Wp[4][8];
#pragma unroll
  for (int g = 0; g < 4; g++) {
    const uint4* p = (const uint4*)(WhP + (size_t)(g * 512 + t) * 32);
#pragma unroll
    for (int m = 0; m < 8; m++) Wp[g][m] = p[m];
  }
  uint4 Up[8];
  {
    const uint4* p = (const uint4*)(UhP + lane * 256 + w * 32);
#pragma unroll
    for (int m = 0; m < 8; m++) Up[m] = p[m];
  }
  const float dia = diah[t];
  float Dg[4], bg[4];
#pragma unroll
  for (int g = 0; g < 4; g++) {
    Dg[g] = Dh[g * 512 + t];
    bg[g] = bh[g * 512 + t];
  }

  float h = 0.f, c = 0.f;
  if (t < 256) h32[t] = 0u;

  const ushort4* gx4 = (const ushort4*)gx;  // [(ts*64+b)*512 + j]
  const size_t gbase = (size_t)b * 512 + t;
  float* outb = out + (size_t)b * 512 + t;

  ushort4 gcur = gx4[gbase];
  __syncthreads();

  for (int ts = 0; ts < 512; ts++) {
    // prefetch next step's gx (independent; lands during A+reduce)
    int tn = ts + (ts < 511);
    ushort4 gnext = gx4[(size_t)tn * 32768 + gbase];

    // ---- stage A: partial hU over chunk w (64 h = 32 pairs), r = lane
    const uint4* hp = ((const uint4*)h32) + w * 8;  // wave-uniform addresses
    float acA = 0.f, acB = 0.f;
#pragma unroll
    for (int m = 0; m < 8; m += 2) {
      uint4 h0 = hp[m], h1 = hp[m + 1];
      uint4 u0 = Up[m], u1 = Up[m + 1];
      acA = dot2f(h0.x, u0.x, acA); acB = dot2f(h1.x, u1.x, acB);
      acA = dot2f(h0.y, u0.y, acA); acB = dot2f(h1.y, u1.y, acB);
      acA = dot2f(h0.z, u0.z, acA); acB = dot2f(h1.z, u1.z, acB);
      acA = dot2f(h0.w, u0.w, acA); acB = dot2f(h1.w, u1.w, acB);
    }
    partial[w * 68 + lane] = acA + acB;
    __syncthreads();

    // ---- per-wave redundant reduce: hu[r=lane] = sum_c partial[c][lane]
    float s0 = partial[0 * 68 + lane] + partial[1 * 68 + lane];
    float s1 = partial[2 * 68 + lane] + partial[3 * 68 + lane];
    float s2 = partial[4 * 68 + lane] + partial[5 * 68 + lane];
    float s3 = partial[6 * 68 + lane] + partial[7 * 68 + lane];
    float hu = (s0 + s1) + (s2 + s3);
    float huo = __shfl_xor(hu, 1, 64);
    if ((lane & 1) == 0) huW[w * 32 + (lane >> 1)] = pk2(hu, huo);
    // same-wave write->read: compiler inserts lgkmcnt, no barrier needed
    const uint4* hup = ((const uint4*)huW) + w * 8;  // wave-uniform

    // ---- stage B: 4 gate dots over all 64 r
    float a0 = 0.f, a1 = 0.f, a2 = 0.f, a3 = 0.f;
#pragma unroll
    for (int m = 0; m < 8; m++) {
      uint4 hm = hup[m];
      uint4 w0 = Wp[0][m], w1 = Wp[1][m], w2 = Wp[2][m], w3 = Wp[3][m];
      a0 = dot2f(hm.x, w0.x, a0); a1 = dot2f(hm.x, w1.x, a1);
      a2 = dot2f(hm.x, w2.x, a2); a3 = dot2f(hm.x, w3.x, a3);
      a0 = dot2f(hm.y, w0.y, a0); a1 = dot2f(hm.y, w1.y, a1);
      a2 = dot2f(hm.y, w2.y, a2); a3 = dot2f(hm.y, w3.y, a3);
      a0 = dot2f(hm.z, w0.z, a0); a1 = dot2f(hm.z, w1.z, a1);
      a2 = dot2f(hm.z, w2.z, a2); a3 = dot2f(hm.z, w3.z, a3);
      a0 = dot2f(hm.w, w0.w, a0); a1 = dot2f(hm.w, w1.w, a1);
      a2 = dot2f(hm.w, w2.w, a2); a3 = dot2f(hm.w, w3.w, a3);
    }
    float hd = h;
    float pre0 = a0 + h2f1(gcur.x) + hd * (dia - Dg[0]) + bg[0];
    float pre1 = a1 + h2f1(gcur.y) + hd * (dia - Dg[1]) + bg[1];
    float pre2 = a2 + h2f1(gcur.z) + hd * (dia - Dg[2]) + bg[2];
    float pre3 = a3 + h2f1(gcur.w) + hd * (dia - Dg[3]) + bg[3];

    float ig = 1.f / (1.f + __expf(-pre0));
    float fg = 1.f / (1.f + __expf(-pre1));
    float og = 1.f / (1.f + __expf(-pre2));
    float e2 = __expf(2.f * pre3);
    float ng = 1.f - 2.f / (e2 + 1.f);
    c = fg * c + ig * ng;
    float e2c = __expf(2.f * c);
    h = og * (1.f - 2.f / (e2c + 1.f));

    outb[(size_t)ts * 32768] = h;
    ((u16*)h32)[t] = f2h(h);
    gcur = gnext;
    __syncthreads();
  }
  out[(size_t)512 * 32768 + (size_t)b * 512 + t] = h;
  out[(size_t)512 * 32768 + 32768 + (size_t)b * 512 + t] = c;
}

// ---------------------------------------------------------------------------
extern "C" void kernel_launch(void* const* d_in, const int* in_sizes, int n_in,
                              void* d_out, int out_size, void* d_ws,
                              size_t ws_size, hipStream_t stream) {
  const float* x = (const float*)d_in[0];
  // d_in[1]=h0, d_in[2]=c0: zeros by construction (recurrence inits 0)
  const float* Ux = (const float*)d_in[3];
  const float* Uh = (const float*)d_in[4];
  const float* Wx = (const float*)d_in[5];
  const float* Wh = (const float*)d_in[6];
  const float* bx = (const float*)d_in[7];
  const float* bh = (const float*)d_in[8];
  const float* diax = (const float*)d_in[9];
  const float* diah = (const float*)d_in[10];
  float* out = (float*)d_out;

  // workspace layout (bytes); total ~139,083,776 B (~132.7 MiB)
  char* ws = (char*)d_ws;
  u16* gx = (u16*)ws;                    // 32768 rows x 512 j x 4 g = 134217728
  u32* xuP = (u32*)(ws + 134217728);     // 32768*32 u32   =   4194304
  u32* WxP = (u32*)(ws + 138412032);     // 65536 u32      =    262144
  u32* WhP = (u32*)(ws + 138674176);     // 65536 u32      =    262144
  u32* UxP = (u32*)(ws + 138936320);     // 16384 u32      =     65536
  u32* UhP = (u32*)(ws + 139001856);     // 16384 u32      =     65536
  float* Dx = (float*)(ws + 139067392);  // 2048 f32       =      8192
  float* Dh = (float*)(ws + 139075584);  // 2048 f32       =      8192

  k0a_pack<<<256, 256, 0, stream>>>(Wx, Wh, Ux, Uh, WxP, WhP, UxP, UhP);
  k0b_diag<<<64, 256, 0, stream>>>(Ux, Uh, Wx, Wh, Dx, Dh);
  k1_xu<<<1024, 256, 0, stream>>>(x, UxP, xuP);
  k2_gx<<<512, 512, 0, stream>>>(x, xuP, WxP, Dx, bx, diax, gx);
  k3_rnn<<<64, 512, 0, stream>>>(gx, WhP, UhP, Dh, bh, diah, out);
}